// Round 2
// baseline (329.817 us; speedup 1.0000x reference)
//
#include <hip/hip_runtime.h>
#include <cstdint>

// ===================== GCN encoder on MI355X =====================
// out = gcn(relu(gcn(x, W1, b1)), W2, b2)
// gcn(x,W,b)[i] = dinv[i] * ( sum_{e: dst=i} (xW*dinv)[src] + (xW*dinv)[i] ) + b
// dinv = rsqrt(indeg+1) (self-loop), identical for both layers.
//
// R8: revert R7 (octant sort + NT hints regressed: 59->65us aggregate).
// Aggregate is latency-bound (VALUBusy 21%, miss-path 3.1 TB/s): attack
// concurrency instead of locality.
//  (a) degree-sorted node permutation (counting sort over rowptr diffs,
//      reusing scancol/scanbucket) -> waves get equal-degree nodes, no
//      divergence tail, full gather issue rate. Per-node sum order
//      unchanged -> bit-identical output.
//  (b) aggregate inner loop: issue all 8 shfls + all 8 uint4 gathers into
//      named regs before accumulating (was VGPR=48 -> compiler had ~2-4
//      loads in flight; now ~8).
// R6 build pipeline + MFMA GEMMs unchanged.

#define BSHIFT 7          // 128 nodes per bucket
#define NBMAX 784         // >= ceil(100000/128) = 782
#define CH 4096           // edges per block in passes A/C
#define MAXB 6016         // LDS-cached bucket capacity (avg 4096, +30 sigma)

typedef __attribute__((ext_vector_type(8))) short bf16x8;
typedef __attribute__((ext_vector_type(4))) float f32x4;

// ---------------- bf16 helpers ----------------
__device__ inline unsigned short f2bf(float f) {
    unsigned u = __float_as_uint(f);
    unsigned r = (u + 0x7FFFu + ((u >> 16) & 1u)) >> 16;  // RNE
    return (unsigned short)r;
}
__device__ inline unsigned pack2(float a, float b) {
    return (unsigned)f2bf(a) | ((unsigned)f2bf(b) << 16);
}
__device__ inline float blo(unsigned u) { return __uint_as_float(u << 16); }
__device__ inline float bhi(unsigned u) { return __uint_as_float(u & 0xFFFF0000u); }

// ---------------- pass A: bucket histogram (+ folded weight prep) ----------
__global__ __launch_bounds__(256) void hist_kernel(const int* __restrict__ dst,
                                                   int* __restrict__ histmat,
                                                   int E, int nb, int nblk,
                                                   const float* __restrict__ W1,
                                                   const float* __restrict__ W2,
                                                   unsigned short* __restrict__ W1t,
                                                   unsigned short* __restrict__ W2t) {
    if (blockIdx.x >= (unsigned)nblk) {
        // weight-prep blocks: W[K][64] fp32 -> Wt[64][K] bf16
        int i = (blockIdx.x - nblk) * 256 + threadIdx.x;
        if (i < 128 * 64) {
            int k = i >> 6, n = i & 63;
            W1t[n * 128 + k] = f2bf(W1[i]);
        }
        int j = i - 128 * 64;
        if (j >= 0 && j < 64 * 64) {
            int k = j >> 6, n = j & 63;
            W2t[n * 64 + k] = f2bf(W2[j]);
        }
        return;
    }
    __shared__ int hist[NBMAX];
    int t = threadIdx.x;
    for (int b = t; b < nb; b += 256) hist[b] = 0;
    __syncthreads();
    int base = blockIdx.x * CH;
#pragma unroll
    for (int j = 0; j < CH / 1024; ++j) {
        int idx = base + j * 1024 + t * 4;
        if (idx + 4 <= E) {
            int4 d = *(const int4*)(dst + idx);
            atomicAdd(&hist[d.x >> BSHIFT], 1);
            atomicAdd(&hist[d.y >> BSHIFT], 1);
            atomicAdd(&hist[d.z >> BSHIFT], 1);
            atomicAdd(&hist[d.w >> BSHIFT], 1);
        } else {
            for (int k = 0; k < 4; ++k)
                if (idx + k < E) atomicAdd(&hist[dst[idx + k] >> BSHIFT], 1);
        }
    }
    __syncthreads();
    for (int b = t; b < nb; b += 256) histmat[blockIdx.x * nb + b] = hist[b];
}

// ---------------- pass B1: per-bucket scan over blocks (nblk <= 1024) -------
__global__ __launch_bounds__(256) void scancol_kernel(const int* __restrict__ histmat,
                                                      int* __restrict__ colbase,
                                                      int* __restrict__ buckettotal,
                                                      int nb, int nblk) {
    __shared__ int ts[256];
    int b = blockIdx.x;
    int t = threadIdx.x;
    int v[4];
    int tsum = 0;
#pragma unroll
    for (int k = 0; k < 4; ++k) {
        int blk = t * 4 + k;
        v[k] = (blk < nblk) ? histmat[blk * nb + b] : 0;
        tsum += v[k];
    }
    ts[t] = tsum;
    __syncthreads();
    for (int ofs = 1; ofs < 256; ofs <<= 1) {
        int val = (t >= ofs) ? ts[t - ofs] : 0;
        __syncthreads();
        ts[t] += val;
        __syncthreads();
    }
    int run = ts[t] - tsum;
#pragma unroll
    for (int k = 0; k < 4; ++k) {
        int blk = t * 4 + k;
        if (blk < nblk) colbase[blk * nb + b] = run;
        run += v[k];
    }
    if (t == 255) buckettotal[b] = ts[255];
}

// ---------------- pass B2: scan bucket totals (single block) ----------------
__global__ __launch_bounds__(256) void scanbucket_kernel(const int* __restrict__ buckettotal,
                                                         int* __restrict__ bucketbase,
                                                         int nb, int E) {
    __shared__ int ts[256];
    int t = threadIdx.x;
    int v[4];
    int tsum = 0;
#pragma unroll
    for (int k = 0; k < 4; ++k) {
        int b = t * 4 + k;
        v[k] = (b < nb) ? buckettotal[b] : 0;
        tsum += v[k];
    }
    ts[t] = tsum;
    __syncthreads();
    for (int ofs = 1; ofs < 256; ofs <<= 1) {
        int val = (t >= ofs) ? ts[t - ofs] : 0;
        __syncthreads();
        ts[t] += val;
        __syncthreads();
    }
    int run = ts[t] - tsum;
#pragma unroll
    for (int k = 0; k < 4; ++k) {
        int b = t * 4 + k;
        if (b < nb) bucketbase[b] = run;
        run += v[k];
    }
    if (t == 0) bucketbase[nb] = E;
}

// ---------------- pass C: scatter into bucket regions (LDS cursors) ---------
__global__ __launch_bounds__(256) void bscatter_kernel(const int* __restrict__ src,
                                                       const int* __restrict__ dst,
                                                       const int* __restrict__ colbase,
                                                       const int* __restrict__ bucketbase,
                                                       int* __restrict__ packed,
                                                       int E, int nb) {
    __shared__ int cur[NBMAX];
    int t = threadIdx.x;
    for (int b = t; b < nb; b += 256)
        cur[b] = bucketbase[b] + colbase[blockIdx.x * nb + b];
    __syncthreads();
    int base = blockIdx.x * CH;
#pragma unroll
    for (int j = 0; j < CH / 1024; ++j) {
        int idx = base + j * 1024 + t * 4;
        if (idx + 4 <= E) {
            int4 d = *(const int4*)(dst + idx);
            int4 s = *(const int4*)(src + idx);
            int p;
            p = atomicAdd(&cur[d.x >> BSHIFT], 1); packed[p] = ((d.x & 127) << 17) | s.x;
            p = atomicAdd(&cur[d.y >> BSHIFT], 1); packed[p] = ((d.y & 127) << 17) | s.y;
            p = atomicAdd(&cur[d.z >> BSHIFT], 1); packed[p] = ((d.z & 127) << 17) | s.z;
            p = atomicAdd(&cur[d.w >> BSHIFT], 1); packed[p] = ((d.w & 127) << 17) | s.w;
        } else {
            for (int k = 0; k < 4; ++k)
                if (idx + k < E) {
                    int dd = dst[idx + k], ss = src[idx + k];
                    int p = atomicAdd(&cur[dd >> BSHIFT], 1);
                    packed[p] = ((dd & 127) << 17) | ss;
                }
        }
    }
}

// ---------------- pass D: within-bucket CSR + rowptr + dinv (LDS-cached) ----
__global__ __launch_bounds__(256) void bcsr_kernel(const int* __restrict__ packed,
                                                   const int* __restrict__ bucketbase,
                                                   int* __restrict__ rowptr,
                                                   float* __restrict__ dinv,
                                                   int* __restrict__ csr,
                                                   int N, int nb) {
    __shared__ int deg[128];
    __shared__ int lrp[128];
    __shared__ int ts[128];
    __shared__ int ebuf[MAXB];
    __shared__ int obuf[MAXB];
    int b = blockIdx.x;
    int t = threadIdx.x;
    if (t < 128) deg[t] = 0;
    __syncthreads();
    int bb0 = bucketbase[b];
    int bb1 = bucketbase[b + 1];
    int cnt = bb1 - bb0;
    bool fits = (cnt <= MAXB);
    if (fits) {
        for (int i = t; i < cnt; i += 256) {
            int v = packed[bb0 + i];
            ebuf[i] = v;
            atomicAdd(&deg[v >> 17], 1);
        }
    } else {
        for (int i = t; i < cnt; i += 256)
            atomicAdd(&deg[packed[bb0 + i] >> 17], 1);
    }
    __syncthreads();
    if (t < 128) ts[t] = deg[t];
    __syncthreads();
    for (int ofs = 1; ofs < 128; ofs <<= 1) {
        int v = (t < 128 && t >= ofs) ? ts[t - ofs] : 0;
        __syncthreads();
        if (t < 128) ts[t] += v;
        __syncthreads();
    }
    int node0 = b << BSHIFT;
    int nlocal = min(128, N - node0);
    if (t < 128) lrp[t] = ts[t] - deg[t];
    if (t < nlocal) {
        rowptr[node0 + t] = bb0 + (ts[t] - deg[t]);
        dinv[node0 + t] = rsqrtf((float)(deg[t] + 1));
    }
    if (t == nlocal) rowptr[node0 + nlocal] = bb1;
    __syncthreads();
    if (fits) {
        for (int i = t; i < cnt; i += 256) {
            int v = ebuf[i];
            int p = atomicAdd(&lrp[v >> 17], 1);
            obuf[p] = v & 0x1FFFF;
        }
        __syncthreads();
        for (int i = t; i < cnt; i += 256) csr[bb0 + i] = obuf[i];  // coalesced
    } else {
        for (int i = t; i < cnt; i += 256) {
            int v = packed[bb0 + i];
            int p = atomicAdd(&lrp[v >> 17], 1);
            csr[bb0 + p] = v & 0x1FFFF;
        }
    }
}

// ------- degree-sort pass 1: per-block degree histogram (1024 nodes/blk) ----
__global__ __launch_bounds__(256) void dhist_kernel(const int* __restrict__ rowptr,
                                                    int* __restrict__ dhistmat, int N) {
    __shared__ int bins[128];
    int t = threadIdx.x;
    if (t < 128) bins[t] = 0;
    __syncthreads();
    int base = blockIdx.x * 1024;
#pragma unroll
    for (int k = 0; k < 4; ++k) {
        int n = base + k * 256 + t;
        if (n < N) {
            int d = rowptr[n + 1] - rowptr[n];
            atomicAdd(&bins[min(d, 127)], 1);
        }
    }
    __syncthreads();
    if (t < 128) dhistmat[blockIdx.x * 128 + t] = bins[t];
}

// ------- degree-sort pass 2: scatter node ids in ascending-degree order -----
__global__ __launch_bounds__(256) void dscatter_kernel(const int* __restrict__ rowptr,
                                                       const int* __restrict__ colbase,
                                                       const int* __restrict__ binbase,
                                                       int* __restrict__ perm, int N) {
    __shared__ int cur[128];
    int t = threadIdx.x;
    if (t < 128) cur[t] = binbase[t] + colbase[blockIdx.x * 128 + t];
    __syncthreads();
    int base = blockIdx.x * 1024;
#pragma unroll
    for (int k = 0; k < 4; ++k) {
        int n = base + k * 256 + t;
        if (n < N) {
            int d = rowptr[n + 1] - rowptr[n];
            int p = atomicAdd(&cur[min(d, 127)], 1);
            perm[p] = n;
        }
    }
}

// ------- MFMA GEMM: Ybf[M,64](bf16) = (X[M,K] @ W[K,64]) * dinv[row] -------
template <int K, bool XBF16>
__global__ __launch_bounds__(256) void gemm_mfma(const void* __restrict__ Xv,
                                                 const unsigned short* __restrict__ Wt,
                                                 const float* __restrict__ dinv,
                                                 unsigned short* __restrict__ Ybf, int M) {
    constexpr int KP = K + 8;
    __shared__ unsigned short Xs[64 * KP];   // reused as Cs (64*72) in epilogue
    __shared__ unsigned short Ws[64 * KP];
    int t = threadIdx.x;
    int row0 = blockIdx.x * 64;

    for (int i = t; i < 64 * K / 8; i += 256) {
        int r = i / (K / 8), c8 = i % (K / 8);
        *(uint4*)(&Ws[r * KP + c8 * 8]) = ((const uint4*)Wt)[i];
    }
    if (XBF16) {
        const unsigned short* X = (const unsigned short*)Xv;
        for (int i = t; i < 64 * K / 8; i += 256) {
            int r = i / (K / 8), c8 = i % (K / 8);
            int gr = row0 + r;
            uint4 v = make_uint4(0u, 0u, 0u, 0u);
            if (gr < M) v = ((const uint4*)(X + (size_t)gr * K))[c8];
            *(uint4*)(&Xs[r * KP + c8 * 8]) = v;
        }
    } else {
        const float* X = (const float*)Xv;
        for (int i = t; i < 64 * K / 4; i += 256) {
            int r = i / (K / 4), c4 = i % (K / 4);
            int gr = row0 + r;
            float4 v = make_float4(0.f, 0.f, 0.f, 0.f);
            if (gr < M) v = ((const float4*)(X + (size_t)gr * K))[c4];
            uint2 p;
            p.x = pack2(v.x, v.y);
            p.y = pack2(v.z, v.w);
            *(uint2*)(&Xs[r * KP + c4 * 4]) = p;
        }
    }
    __syncthreads();

    int lane = t & 63;
    int w = t >> 6;
    int m = lane & 15;
    int q = lane >> 4;

    f32x4 acc[4];
#pragma unroll
    for (int nt = 0; nt < 4; ++nt) acc[nt] = (f32x4){0.f, 0.f, 0.f, 0.f};

#pragma unroll
    for (int s = 0; s < K / 32; ++s) {
        bf16x8 a = *(const bf16x8*)(&Xs[(16 * w + m) * KP + s * 32 + q * 8]);
#pragma unroll
        for (int nt = 0; nt < 4; ++nt) {
            bf16x8 b = *(const bf16x8*)(&Ws[(16 * nt + m) * KP + s * 32 + q * 8]);
            acc[nt] = __builtin_amdgcn_mfma_f32_16x16x32_bf16(a, b, acc[nt], 0, 0, 0);
        }
    }
    __syncthreads();

    unsigned short* Cs = Xs;
#pragma unroll
    for (int nt = 0; nt < 4; ++nt)
#pragma unroll
        for (int r = 0; r < 4; ++r) {
            int row = 16 * w + q * 4 + r;
            int gr = row0 + row;
            float d = (gr < M) ? dinv[gr] : 0.f;
            Cs[row * 72 + nt * 16 + m] = f2bf(acc[nt][r] * d);
        }
    __syncthreads();
    for (int i = t; i < 64 * 64 / 8; i += 256) {
        int r = i >> 3, c8 = i & 7;
        int gr = row0 + r;
        if (gr < M)
            *(uint4*)(Ybf + (size_t)gr * 64 + c8 * 8) = *(const uint4*)(&Cs[r * 72 + c8 * 8]);
    }
}

// ---------------- pull aggregation + epilogue (degree-sorted order) ---------
#define ACC8(v)                                      \
    acc[0] += blo(v.x); acc[1] += bhi(v.x);          \
    acc[2] += blo(v.y); acc[3] += bhi(v.y);          \
    acc[4] += blo(v.z); acc[5] += bhi(v.z);          \
    acc[6] += blo(v.w); acc[7] += bhi(v.w);

__global__ __launch_bounds__(256) void aggregate_kernel(const unsigned* __restrict__ hsu,
                                                        const int* __restrict__ rowptr,
                                                        const int* __restrict__ csr,
                                                        const int* __restrict__ perm,
                                                        const float* __restrict__ dinv,
                                                        const float* __restrict__ bias,
                                                        void* __restrict__ outv, int N,
                                                        int do_relu, int obf) {
    int t = threadIdx.x;
    int slot = blockIdx.x * 32 + (t >> 3);
    if (slot >= N) return;
    int node = perm[slot];  // ascending-degree order: waves get equal trip counts
    int sub = t & 7;
    int gbase = t & 56;

    float acc[8];
    {
        uint4 v = *(const uint4*)(hsu + (size_t)node * 32 + sub * 4);  // self-loop
        acc[0] = blo(v.x); acc[1] = bhi(v.x);
        acc[2] = blo(v.y); acc[3] = bhi(v.y);
        acc[4] = blo(v.z); acc[5] = bhi(v.z);
        acc[6] = blo(v.w); acc[7] = bhi(v.w);
    }
    int e0 = rowptr[node];
    int e1 = rowptr[node + 1];

    int e = e0;
    for (; e + 8 <= e1; e += 8) {
        int idx = csr[e + sub];
        // issue all shfls, then all 8 independent gathers, then accumulate:
        // keeps ~8 16B loads in flight per wave (latency-bound regime).
        int s0 = __shfl(idx, gbase + 0, 64);
        int s1 = __shfl(idx, gbase + 1, 64);
        int s2 = __shfl(idx, gbase + 2, 64);
        int s3 = __shfl(idx, gbase + 3, 64);
        int s4 = __shfl(idx, gbase + 4, 64);
        int s5 = __shfl(idx, gbase + 5, 64);
        int s6 = __shfl(idx, gbase + 6, 64);
        int s7 = __shfl(idx, gbase + 7, 64);
        uint4 v0 = *(const uint4*)(hsu + (size_t)s0 * 32 + sub * 4);
        uint4 v1 = *(const uint4*)(hsu + (size_t)s1 * 32 + sub * 4);
        uint4 v2 = *(const uint4*)(hsu + (size_t)s2 * 32 + sub * 4);
        uint4 v3 = *(const uint4*)(hsu + (size_t)s3 * 32 + sub * 4);
        uint4 v4 = *(const uint4*)(hsu + (size_t)s4 * 32 + sub * 4);
        uint4 v5 = *(const uint4*)(hsu + (size_t)s5 * 32 + sub * 4);
        uint4 v6 = *(const uint4*)(hsu + (size_t)s6 * 32 + sub * 4);
        uint4 v7 = *(const uint4*)(hsu + (size_t)s7 * 32 + sub * 4);
        ACC8(v0); ACC8(v1); ACC8(v2); ACC8(v3);
        ACC8(v4); ACC8(v5); ACC8(v6); ACC8(v7);
    }
    for (; e < e1; ++e) {
        int s = csr[e];
        uint4 v = *(const uint4*)(hsu + (size_t)s * 32 + sub * 4);
        ACC8(v);
    }

    float d = dinv[node];
    float4 b0 = *(const float4*)(bias + sub * 8);
    float4 b1 = *(const float4*)(bias + sub * 8 + 4);
    float o[8];
    o[0] = fmaf(acc[0], d, b0.x); o[1] = fmaf(acc[1], d, b0.y);
    o[2] = fmaf(acc[2], d, b0.z); o[3] = fmaf(acc[3], d, b0.w);
    o[4] = fmaf(acc[4], d, b1.x); o[5] = fmaf(acc[5], d, b1.y);
    o[6] = fmaf(acc[6], d, b1.z); o[7] = fmaf(acc[7], d, b1.w);
    if (do_relu) {
#pragma unroll
        for (int k = 0; k < 8; ++k) o[k] = fmaxf(o[k], 0.f);
    }
    if (obf) {
        unsigned short* outb = (unsigned short*)outv;
        uint4 p;
        p.x = pack2(o[0], o[1]); p.y = pack2(o[2], o[3]);
        p.z = pack2(o[4], o[5]); p.w = pack2(o[6], o[7]);
        *(uint4*)(outb + (size_t)node * 64 + sub * 8) = p;
    } else {
        float* op = (float*)outv + (size_t)node * 64 + sub * 8;
        *(float4*)(op)     = make_float4(o[0], o[1], o[2], o[3]);
        *(float4*)(op + 4) = make_float4(o[4], o[5], o[6], o[7]);
    }
}

// ---------------- launch ----------------
extern "C" void kernel_launch(void* const* d_in, const int* in_sizes, int n_in,
                              void* d_out, int out_size, void* d_ws, size_t ws_size,
                              hipStream_t stream) {
    const float* x  = (const float*)d_in[0];
    const int*   ei = (const int*)d_in[1];   // [2, E] int32
    const float* W1 = (const float*)d_in[2];
    const float* b1 = (const float*)d_in[3];
    const float* W2 = (const float*)d_in[4];
    const float* b2 = (const float*)d_in[5];

    const int N = in_sizes[0] / 128;  // 100000
    const int E = in_sizes[1] / 2;    // 3200000
    const int* src = ei;
    const int* dst = ei + E;
    float* out = (float*)d_out;

    const int nb   = (N + 127) >> BSHIFT;  // 782
    const int nblk = (E + CH - 1) / CH;    // 782
    const int nblkD = (N + 1023) / 1024;   // 98 (degree-sort blocks)

    char* ws = (char*)d_ws;
    size_t off = 0;
    auto alloc = [&](size_t bytes) -> char* {
        char* p = ws + off;
        off = (off + bytes + 255) & ~(size_t)255;
        return p;
    };
    // persistent
    int*   csr         = (int*)alloc((size_t)E * 4);
    int*   rowptr      = (int*)alloc((size_t)(N + 1) * 4);
    float* dinv        = (float*)alloc((size_t)N * 4);
    int*   bucketbase  = (int*)alloc((size_t)(nb + 1) * 4);
    int*   buckettotal = (int*)alloc((size_t)nb * 4);
    int*   perm        = (int*)alloc((size_t)N * 4);
    int*   dbinbase    = (int*)alloc(129 * 4);
    int*   dbintotal   = (int*)alloc(128 * 4);
    unsigned short* W1t = (unsigned short*)alloc(64 * 128 * 2);
    unsigned short* W2t = (unsigned short*)alloc(64 * 64 * 2);
    unsigned short* bufA = (unsigned short*)alloc((size_t)N * 64 * 2);  // bf16 h*dinv
    unsigned short* bufB = (unsigned short*)alloc((size_t)N * 64 * 2);  // bf16 relu(agg1)
    // transient (dead before gemm1 writes bufA) — alias bufA+bufB region
    // histmat: nblk*nb*4 ~ 2.45 MB; packed: E*4 = 12.8 MB; dhistmat: 50 KB
    int* histmat  = (int*)bufA;
    int* packed   = (int*)((char*)bufA + ((size_t)nblk * nb * 4 + 255 & ~(size_t)255) + 256);
    int* dhistmat = packed + E;

    hist_kernel<<<nblk + 48, 256, 0, stream>>>(dst, histmat, E, nb, nblk, W1, W2, W1t, W2t);
    scancol_kernel<<<nb, 256, 0, stream>>>(histmat, histmat, buckettotal, nb, nblk);
    scanbucket_kernel<<<1, 256, 0, stream>>>(buckettotal, bucketbase, nb, E);
    bscatter_kernel<<<nblk, 256, 0, stream>>>(src, dst, histmat, bucketbase, packed, E, nb);
    bcsr_kernel<<<nb, 256, 0, stream>>>(packed, bucketbase, rowptr, dinv, csr, N, nb);

    // degree-sorted permutation (reuses the scan kernels on 128 bins x nblkD)
    dhist_kernel<<<nblkD, 256, 0, stream>>>(rowptr, dhistmat, N);
    scancol_kernel<<<128, 256, 0, stream>>>(dhistmat, dhistmat, dbintotal, 128, nblkD);
    scanbucket_kernel<<<1, 256, 0, stream>>>(dbintotal, dbinbase, 128, N);
    dscatter_kernel<<<nblkD, 256, 0, stream>>>(rowptr, dhistmat, dbinbase, perm, N);

    gemm_mfma<128, false><<<(N + 63) / 64, 256, 0, stream>>>(x, W1t, dinv, bufA, N);
    aggregate_kernel<<<(N + 31) / 32, 256, 0, stream>>>((const unsigned*)bufA, rowptr, csr,
                                                        perm, dinv, b1, bufB, N, 1, 1);
    gemm_mfma<64, true><<<(N + 63) / 64, 256, 0, stream>>>(bufB, W2t, dinv, bufA, N);
    aggregate_kernel<<<(N + 31) / 32, 256, 0, stream>>>((const unsigned*)bufA, rowptr, csr,
                                                        perm, dinv, b2, out, N, 0, 0);
}

// Round 3
// 320.139 us; speedup vs baseline: 1.0302x; 1.0302x over previous
//
#include <hip/hip_runtime.h>
#include <cstdint>

// ===================== GCN encoder on MI355X =====================
// out = gcn(relu(gcn(x, W1, b1)), W2, b2)
// gcn(x,W,b)[i] = dinv[i] * ( sum_{e: dst=i} (xW*dinv)[src] + (xW*dinv)[i] ) + b
// dinv = rsqrt(indeg+1) (self-loop), identical for both layers.
//
// R9: aggregate is at its structural floor (~58.5us: 410 MB random 128B
// gathers at blended L2/LLC rate ~7 TB/s effective; per-XCD L2 replication
// puts the fetch floor at 8x12.8=102 MB vs measured 177 MB; R7/R8 attacks
// all landed within 1%). So: revert degree-sort (-11us, was pure overhead)
// and trim the build pipeline instead: CH 4096->8192 halves the number of
// per-(block,bucket) scatter streams in bscatter (611K->306K partial-line
// write-allocations) and halves histmat traffic.
// R6 MFMA GEMMs + bcsr unchanged; aggregate keeps the (neutral) 8-batch.

#define BSHIFT 7          // 128 nodes per bucket
#define NBMAX 784         // >= ceil(100000/128) = 782
#define CH 8192           // edges per block in passes A/C
#define MAXB 6016         // LDS-cached bucket capacity (avg 4096, +30 sigma)

typedef __attribute__((ext_vector_type(8))) short bf16x8;
typedef __attribute__((ext_vector_type(4))) float f32x4;

// ---------------- bf16 helpers ----------------
__device__ inline unsigned short f2bf(float f) {
    unsigned u = __float_as_uint(f);
    unsigned r = (u + 0x7FFFu + ((u >> 16) & 1u)) >> 16;  // RNE
    return (unsigned short)r;
}
__device__ inline unsigned pack2(float a, float b) {
    return (unsigned)f2bf(a) | ((unsigned)f2bf(b) << 16);
}
__device__ inline float blo(unsigned u) { return __uint_as_float(u << 16); }
__device__ inline float bhi(unsigned u) { return __uint_as_float(u & 0xFFFF0000u); }

// ---------------- pass A: bucket histogram (+ folded weight prep) ----------
__global__ __launch_bounds__(256) void hist_kernel(const int* __restrict__ dst,
                                                   int* __restrict__ histmat,
                                                   int E, int nb, int nblk,
                                                   const float* __restrict__ W1,
                                                   const float* __restrict__ W2,
                                                   unsigned short* __restrict__ W1t,
                                                   unsigned short* __restrict__ W2t) {
    if (blockIdx.x >= (unsigned)nblk) {
        // weight-prep blocks: W[K][64] fp32 -> Wt[64][K] bf16
        int i = (blockIdx.x - nblk) * 256 + threadIdx.x;
        if (i < 128 * 64) {
            int k = i >> 6, n = i & 63;
            W1t[n * 128 + k] = f2bf(W1[i]);
        }
        int j = i - 128 * 64;
        if (j >= 0 && j < 64 * 64) {
            int k = j >> 6, n = j & 63;
            W2t[n * 64 + k] = f2bf(W2[j]);
        }
        return;
    }
    __shared__ int hist[NBMAX];
    int t = threadIdx.x;
    for (int b = t; b < nb; b += 256) hist[b] = 0;
    __syncthreads();
    int base = blockIdx.x * CH;
#pragma unroll
    for (int j = 0; j < CH / 1024; ++j) {
        int idx = base + j * 1024 + t * 4;
        if (idx + 4 <= E) {
            int4 d = *(const int4*)(dst + idx);
            atomicAdd(&hist[d.x >> BSHIFT], 1);
            atomicAdd(&hist[d.y >> BSHIFT], 1);
            atomicAdd(&hist[d.z >> BSHIFT], 1);
            atomicAdd(&hist[d.w >> BSHIFT], 1);
        } else {
            for (int k = 0; k < 4; ++k)
                if (idx + k < E) atomicAdd(&hist[dst[idx + k] >> BSHIFT], 1);
        }
    }
    __syncthreads();
    for (int b = t; b < nb; b += 256) histmat[blockIdx.x * nb + b] = hist[b];
}

// ---------------- pass B1: per-bucket scan over blocks (nblk <= 1024) -------
__global__ __launch_bounds__(256) void scancol_kernel(const int* __restrict__ histmat,
                                                      int* __restrict__ colbase,
                                                      int* __restrict__ buckettotal,
                                                      int nb, int nblk) {
    __shared__ int ts[256];
    int b = blockIdx.x;
    int t = threadIdx.x;
    int v[4];
    int tsum = 0;
#pragma unroll
    for (int k = 0; k < 4; ++k) {
        int blk = t * 4 + k;
        v[k] = (blk < nblk) ? histmat[blk * nb + b] : 0;
        tsum += v[k];
    }
    ts[t] = tsum;
    __syncthreads();
    for (int ofs = 1; ofs < 256; ofs <<= 1) {
        int val = (t >= ofs) ? ts[t - ofs] : 0;
        __syncthreads();
        ts[t] += val;
        __syncthreads();
    }
    int run = ts[t] - tsum;
#pragma unroll
    for (int k = 0; k < 4; ++k) {
        int blk = t * 4 + k;
        if (blk < nblk) colbase[blk * nb + b] = run;
        run += v[k];
    }
    if (t == 255) buckettotal[b] = ts[255];
}

// ---------------- pass B2: scan bucket totals (single block) ----------------
__global__ __launch_bounds__(256) void scanbucket_kernel(const int* __restrict__ buckettotal,
                                                         int* __restrict__ bucketbase,
                                                         int nb, int E) {
    __shared__ int ts[256];
    int t = threadIdx.x;
    int v[4];
    int tsum = 0;
#pragma unroll
    for (int k = 0; k < 4; ++k) {
        int b = t * 4 + k;
        v[k] = (b < nb) ? buckettotal[b] : 0;
        tsum += v[k];
    }
    ts[t] = tsum;
    __syncthreads();
    for (int ofs = 1; ofs < 256; ofs <<= 1) {
        int val = (t >= ofs) ? ts[t - ofs] : 0;
        __syncthreads();
        ts[t] += val;
        __syncthreads();
    }
    int run = ts[t] - tsum;
#pragma unroll
    for (int k = 0; k < 4; ++k) {
        int b = t * 4 + k;
        if (b < nb) bucketbase[b] = run;
        run += v[k];
    }
    if (t == 0) bucketbase[nb] = E;
}

// ---------------- pass C: scatter into bucket regions (LDS cursors) ---------
__global__ __launch_bounds__(256) void bscatter_kernel(const int* __restrict__ src,
                                                       const int* __restrict__ dst,
                                                       const int* __restrict__ colbase,
                                                       const int* __restrict__ bucketbase,
                                                       int* __restrict__ packed,
                                                       int E, int nb) {
    __shared__ int cur[NBMAX];
    int t = threadIdx.x;
    for (int b = t; b < nb; b += 256)
        cur[b] = bucketbase[b] + colbase[blockIdx.x * nb + b];
    __syncthreads();
    int base = blockIdx.x * CH;
#pragma unroll
    for (int j = 0; j < CH / 1024; ++j) {
        int idx = base + j * 1024 + t * 4;
        if (idx + 4 <= E) {
            int4 d = *(const int4*)(dst + idx);
            int4 s = *(const int4*)(src + idx);
            int p;
            p = atomicAdd(&cur[d.x >> BSHIFT], 1); packed[p] = ((d.x & 127) << 17) | s.x;
            p = atomicAdd(&cur[d.y >> BSHIFT], 1); packed[p] = ((d.y & 127) << 17) | s.y;
            p = atomicAdd(&cur[d.z >> BSHIFT], 1); packed[p] = ((d.z & 127) << 17) | s.z;
            p = atomicAdd(&cur[d.w >> BSHIFT], 1); packed[p] = ((d.w & 127) << 17) | s.w;
        } else {
            for (int k = 0; k < 4; ++k)
                if (idx + k < E) {
                    int dd = dst[idx + k], ss = src[idx + k];
                    int p = atomicAdd(&cur[dd >> BSHIFT], 1);
                    packed[p] = ((dd & 127) << 17) | ss;
                }
        }
    }
}

// ---------------- pass D: within-bucket CSR + rowptr + dinv (LDS-cached) ----
__global__ __launch_bounds__(256) void bcsr_kernel(const int* __restrict__ packed,
                                                   const int* __restrict__ bucketbase,
                                                   int* __restrict__ rowptr,
                                                   float* __restrict__ dinv,
                                                   int* __restrict__ csr,
                                                   int N, int nb) {
    __shared__ int deg[128];
    __shared__ int lrp[128];
    __shared__ int ts[128];
    __shared__ int ebuf[MAXB];
    __shared__ int obuf[MAXB];
    int b = blockIdx.x;
    int t = threadIdx.x;
    if (t < 128) deg[t] = 0;
    __syncthreads();
    int bb0 = bucketbase[b];
    int bb1 = bucketbase[b + 1];
    int cnt = bb1 - bb0;
    bool fits = (cnt <= MAXB);
    if (fits) {
        for (int i = t; i < cnt; i += 256) {
            int v = packed[bb0 + i];
            ebuf[i] = v;
            atomicAdd(&deg[v >> 17], 1);
        }
    } else {
        for (int i = t; i < cnt; i += 256)
            atomicAdd(&deg[packed[bb0 + i] >> 17], 1);
    }
    __syncthreads();
    if (t < 128) ts[t] = deg[t];
    __syncthreads();
    for (int ofs = 1; ofs < 128; ofs <<= 1) {
        int v = (t < 128 && t >= ofs) ? ts[t - ofs] : 0;
        __syncthreads();
        if (t < 128) ts[t] += v;
        __syncthreads();
    }
    int node0 = b << BSHIFT;
    int nlocal = min(128, N - node0);
    if (t < 128) lrp[t] = ts[t] - deg[t];
    if (t < nlocal) {
        rowptr[node0 + t] = bb0 + (ts[t] - deg[t]);
        dinv[node0 + t] = rsqrtf((float)(deg[t] + 1));
    }
    if (t == nlocal) rowptr[node0 + nlocal] = bb1;
    __syncthreads();
    if (fits) {
        for (int i = t; i < cnt; i += 256) {
            int v = ebuf[i];
            int p = atomicAdd(&lrp[v >> 17], 1);
            obuf[p] = v & 0x1FFFF;
        }
        __syncthreads();
        for (int i = t; i < cnt; i += 256) csr[bb0 + i] = obuf[i];  // coalesced
    } else {
        for (int i = t; i < cnt; i += 256) {
            int v = packed[bb0 + i];
            int p = atomicAdd(&lrp[v >> 17], 1);
            csr[bb0 + p] = v & 0x1FFFF;
        }
    }
}

// ------- MFMA GEMM: Ybf[M,64](bf16) = (X[M,K] @ W[K,64]) * dinv[row] -------
template <int K, bool XBF16>
__global__ __launch_bounds__(256) void gemm_mfma(const void* __restrict__ Xv,
                                                 const unsigned short* __restrict__ Wt,
                                                 const float* __restrict__ dinv,
                                                 unsigned short* __restrict__ Ybf, int M) {
    constexpr int KP = K + 8;
    __shared__ unsigned short Xs[64 * KP];   // reused as Cs (64*72) in epilogue
    __shared__ unsigned short Ws[64 * KP];
    int t = threadIdx.x;
    int row0 = blockIdx.x * 64;

    for (int i = t; i < 64 * K / 8; i += 256) {
        int r = i / (K / 8), c8 = i % (K / 8);
        *(uint4*)(&Ws[r * KP + c8 * 8]) = ((const uint4*)Wt)[i];
    }
    if (XBF16) {
        const unsigned short* X = (const unsigned short*)Xv;
        for (int i = t; i < 64 * K / 8; i += 256) {
            int r = i / (K / 8), c8 = i % (K / 8);
            int gr = row0 + r;
            uint4 v = make_uint4(0u, 0u, 0u, 0u);
            if (gr < M) v = ((const uint4*)(X + (size_t)gr * K))[c8];
            *(uint4*)(&Xs[r * KP + c8 * 8]) = v;
        }
    } else {
        const float* X = (const float*)Xv;
        for (int i = t; i < 64 * K / 4; i += 256) {
            int r = i / (K / 4), c4 = i % (K / 4);
            int gr = row0 + r;
            float4 v = make_float4(0.f, 0.f, 0.f, 0.f);
            if (gr < M) v = ((const float4*)(X + (size_t)gr * K))[c4];
            uint2 p;
            p.x = pack2(v.x, v.y);
            p.y = pack2(v.z, v.w);
            *(uint2*)(&Xs[r * KP + c4 * 4]) = p;
        }
    }
    __syncthreads();

    int lane = t & 63;
    int w = t >> 6;
    int m = lane & 15;
    int q = lane >> 4;

    f32x4 acc[4];
#pragma unroll
    for (int nt = 0; nt < 4; ++nt) acc[nt] = (f32x4){0.f, 0.f, 0.f, 0.f};

#pragma unroll
    for (int s = 0; s < K / 32; ++s) {
        bf16x8 a = *(const bf16x8*)(&Xs[(16 * w + m) * KP + s * 32 + q * 8]);
#pragma unroll
        for (int nt = 0; nt < 4; ++nt) {
            bf16x8 b = *(const bf16x8*)(&Ws[(16 * nt + m) * KP + s * 32 + q * 8]);
            acc[nt] = __builtin_amdgcn_mfma_f32_16x16x32_bf16(a, b, acc[nt], 0, 0, 0);
        }
    }
    __syncthreads();

    unsigned short* Cs = Xs;
#pragma unroll
    for (int nt = 0; nt < 4; ++nt)
#pragma unroll
        for (int r = 0; r < 4; ++r) {
            int row = 16 * w + q * 4 + r;
            int gr = row0 + row;
            float d = (gr < M) ? dinv[gr] : 0.f;
            Cs[row * 72 + nt * 16 + m] = f2bf(acc[nt][r] * d);
        }
    __syncthreads();
    for (int i = t; i < 64 * 64 / 8; i += 256) {
        int r = i >> 3, c8 = i & 7;
        int gr = row0 + r;
        if (gr < M)
            *(uint4*)(Ybf + (size_t)gr * 64 + c8 * 8) = *(const uint4*)(&Cs[r * 72 + c8 * 8]);
    }
}

// ---------------- pull aggregation + epilogue ----------------
#define ACC8(v)                                      \
    acc[0] += blo(v.x); acc[1] += bhi(v.x);          \
    acc[2] += blo(v.y); acc[3] += bhi(v.y);          \
    acc[4] += blo(v.z); acc[5] += bhi(v.z);          \
    acc[6] += blo(v.w); acc[7] += bhi(v.w);

__global__ __launch_bounds__(256) void aggregate_kernel(const unsigned* __restrict__ hsu,
                                                        const int* __restrict__ rowptr,
                                                        const int* __restrict__ csr,
                                                        const float* __restrict__ dinv,
                                                        const float* __restrict__ bias,
                                                        void* __restrict__ outv, int N,
                                                        int do_relu, int obf) {
    int t = threadIdx.x;
    int node = blockIdx.x * 32 + (t >> 3);
    if (node >= N) return;
    int sub = t & 7;
    int gbase = t & 56;

    float acc[8];
    {
        uint4 v = *(const uint4*)(hsu + (size_t)node * 32 + sub * 4);  // self-loop
        acc[0] = blo(v.x); acc[1] = bhi(v.x);
        acc[2] = blo(v.y); acc[3] = bhi(v.y);
        acc[4] = blo(v.z); acc[5] = bhi(v.z);
        acc[6] = blo(v.w); acc[7] = bhi(v.w);
    }
    int e0 = rowptr[node];
    int e1 = rowptr[node + 1];

    int e = e0;
    for (; e + 8 <= e1; e += 8) {
        int idx = csr[e + sub];
        int s0 = __shfl(idx, gbase + 0, 64);
        int s1 = __shfl(idx, gbase + 1, 64);
        int s2 = __shfl(idx, gbase + 2, 64);
        int s3 = __shfl(idx, gbase + 3, 64);
        int s4 = __shfl(idx, gbase + 4, 64);
        int s5 = __shfl(idx, gbase + 5, 64);
        int s6 = __shfl(idx, gbase + 6, 64);
        int s7 = __shfl(idx, gbase + 7, 64);
        uint4 v0 = *(const uint4*)(hsu + (size_t)s0 * 32 + sub * 4);
        uint4 v1 = *(const uint4*)(hsu + (size_t)s1 * 32 + sub * 4);
        uint4 v2 = *(const uint4*)(hsu + (size_t)s2 * 32 + sub * 4);
        uint4 v3 = *(const uint4*)(hsu + (size_t)s3 * 32 + sub * 4);
        uint4 v4 = *(const uint4*)(hsu + (size_t)s4 * 32 + sub * 4);
        uint4 v5 = *(const uint4*)(hsu + (size_t)s5 * 32 + sub * 4);
        uint4 v6 = *(const uint4*)(hsu + (size_t)s6 * 32 + sub * 4);
        uint4 v7 = *(const uint4*)(hsu + (size_t)s7 * 32 + sub * 4);
        ACC8(v0); ACC8(v1); ACC8(v2); ACC8(v3);
        ACC8(v4); ACC8(v5); ACC8(v6); ACC8(v7);
    }
    for (; e < e1; ++e) {
        int s = csr[e];
        uint4 v = *(const uint4*)(hsu + (size_t)s * 32 + sub * 4);
        ACC8(v);
    }

    float d = dinv[node];
    float4 b0 = *(const float4*)(bias + sub * 8);
    float4 b1 = *(const float4*)(bias + sub * 8 + 4);
    float o[8];
    o[0] = fmaf(acc[0], d, b0.x); o[1] = fmaf(acc[1], d, b0.y);
    o[2] = fmaf(acc[2], d, b0.z); o[3] = fmaf(acc[3], d, b0.w);
    o[4] = fmaf(acc[4], d, b1.x); o[5] = fmaf(acc[5], d, b1.y);
    o[6] = fmaf(acc[6], d, b1.z); o[7] = fmaf(acc[7], d, b1.w);
    if (do_relu) {
#pragma unroll
        for (int k = 0; k < 8; ++k) o[k] = fmaxf(o[k], 0.f);
    }
    if (obf) {
        unsigned short* outb = (unsigned short*)outv;
        uint4 p;
        p.x = pack2(o[0], o[1]); p.y = pack2(o[2], o[3]);
        p.z = pack2(o[4], o[5]); p.w = pack2(o[6], o[7]);
        *(uint4*)(outb + (size_t)node * 64 + sub * 8) = p;
    } else {
        float* op = (float*)outv + (size_t)node * 64 + sub * 8;
        *(float4*)(op)     = make_float4(o[0], o[1], o[2], o[3]);
        *(float4*)(op + 4) = make_float4(o[4], o[5], o[6], o[7]);
    }
}

// ---------------- launch ----------------
extern "C" void kernel_launch(void* const* d_in, const int* in_sizes, int n_in,
                              void* d_out, int out_size, void* d_ws, size_t ws_size,
                              hipStream_t stream) {
    const float* x  = (const float*)d_in[0];
    const int*   ei = (const int*)d_in[1];   // [2, E] int32
    const float* W1 = (const float*)d_in[2];
    const float* b1 = (const float*)d_in[3];
    const float* W2 = (const float*)d_in[4];
    const float* b2 = (const float*)d_in[5];

    const int N = in_sizes[0] / 128;  // 100000
    const int E = in_sizes[1] / 2;    // 3200000
    const int* src = ei;
    const int* dst = ei + E;
    float* out = (float*)d_out;

    const int nb   = (N + 127) >> BSHIFT;  // 782
    const int nblk = (E + CH - 1) / CH;    // 391

    char* ws = (char*)d_ws;
    size_t off = 0;
    auto alloc = [&](size_t bytes) -> char* {
        char* p = ws + off;
        off = (off + bytes + 255) & ~(size_t)255;
        return p;
    };
    // persistent
    int*   csr         = (int*)alloc((size_t)E * 4);
    int*   rowptr      = (int*)alloc((size_t)(N + 1) * 4);
    float* dinv        = (float*)alloc((size_t)N * 4);
    int*   bucketbase  = (int*)alloc((size_t)(nb + 1) * 4);
    int*   buckettotal = (int*)alloc((size_t)nb * 4);
    unsigned short* W1t = (unsigned short*)alloc(64 * 128 * 2);
    unsigned short* W2t = (unsigned short*)alloc(64 * 64 * 2);
    unsigned short* bufA = (unsigned short*)alloc((size_t)N * 64 * 2);  // bf16 h*dinv
    unsigned short* bufB = (unsigned short*)alloc((size_t)N * 64 * 2);  // bf16 relu(agg1)
    // transient (dead before gemm1 writes bufA) — alias bufA+bufB region
    // histmat: nblk*nb*4 = 391*782*4 ~ 1.22 MB; packed: E*4 = 12.8 MB
    int* histmat = (int*)bufA;
    int* packed  = (int*)((char*)bufA + ((size_t)nblk * nb * 4 + 255 & ~(size_t)255) + 256);

    hist_kernel<<<nblk + 48, 256, 0, stream>>>(dst, histmat, E, nb, nblk, W1, W2, W1t, W2t);
    scancol_kernel<<<nb, 256, 0, stream>>>(histmat, histmat, buckettotal, nb, nblk);
    scanbucket_kernel<<<1, 256, 0, stream>>>(buckettotal, bucketbase, nb, E);
    bscatter_kernel<<<nblk, 256, 0, stream>>>(src, dst, histmat, bucketbase, packed, E, nb);
    bcsr_kernel<<<nb, 256, 0, stream>>>(packed, bucketbase, rowptr, dinv, csr, N, nb);

    gemm_mfma<128, false><<<(N + 63) / 64, 256, 0, stream>>>(x, W1t, dinv, bufA, N);
    aggregate_kernel<<<(N + 31) / 32, 256, 0, stream>>>((const unsigned*)bufA, rowptr, csr,
                                                        dinv, b1, bufB, N, 1, 1);
    gemm_mfma<64, true><<<(N + 63) / 64, 256, 0, stream>>>(bufB, W2t, dinv, bufA, N);
    aggregate_kernel<<<(N + 31) / 32, 256, 0, stream>>>((const unsigned*)bufA, rowptr, csr,
                                                        dinv, b2, out, N, 0, 0);
}

// Round 4
// 310.207 us; speedup vs baseline: 1.0632x; 1.0320x over previous
//
#include <hip/hip_runtime.h>
#include <cstdint>

// ===================== GCN encoder on MI355X =====================
// out = gcn(relu(gcn(x, W1, b1)), W2, b2)
// gcn(x,W,b)[i] = dinv[i] * ( sum_{e: dst=i} (xW*dinv)[src] + (xW*dinv)[i] ) + b
// dinv = rsqrt(indeg+1) (self-loop), identical for both layers.
//
// R10: dispatch-count attack (aggregate itself is at its ~59us floor:
// 4 variants R6-R9 within 1%, FETCH stable ~165-177MB at ~2.8 TB/s L2-miss
// path; 12.8MB table replicated over 8x4MiB L2s is structural).
//  (a) gemm2 fused into aggregate1: block's 32 nodes' hidden vectors ->
//      bf16 (same rounding as old bufB) -> LDS -> 8 MFMA tiles -> *dinv
//      -> bufB. Removes gemm2 dispatch + 25.6MB of bufB round-trip.
//  (b) scanbucket removed: bscatter/bcsr replicate the 782-wide
//      buckettotal scan in-block (3KB L2-hot read, ~free).
// 9 -> 7 dispatches. Build pipeline otherwise R9 (CH=8192).

#define BSHIFT 7          // 128 nodes per bucket
#define NBMAX 784         // >= ceil(100000/128) = 782
#define CH 8192           // edges per block in passes A/C
#define MAXB 6016         // LDS-cached bucket capacity (avg 4096, +30 sigma)

typedef __attribute__((ext_vector_type(8))) short bf16x8;
typedef __attribute__((ext_vector_type(4))) float f32x4;

// ---------------- bf16 helpers ----------------
__device__ inline unsigned short f2bf(float f) {
    unsigned u = __float_as_uint(f);
    unsigned r = (u + 0x7FFFu + ((u >> 16) & 1u)) >> 16;  // RNE
    return (unsigned short)r;
}
__device__ inline unsigned pack2(float a, float b) {
    return (unsigned)f2bf(a) | ((unsigned)f2bf(b) << 16);
}
__device__ inline float blo(unsigned u) { return __uint_as_float(u << 16); }
__device__ inline float bhi(unsigned u) { return __uint_as_float(u & 0xFFFF0000u); }

// ---------------- pass A: bucket histogram (+ folded weight prep) ----------
__global__ __launch_bounds__(256) void hist_kernel(const int* __restrict__ dst,
                                                   int* __restrict__ histmat,
                                                   int E, int nb, int nblk,
                                                   const float* __restrict__ W1,
                                                   const float* __restrict__ W2,
                                                   unsigned short* __restrict__ W1t,
                                                   unsigned short* __restrict__ W2t) {
    if (blockIdx.x >= (unsigned)nblk) {
        // weight-prep blocks: W[K][64] fp32 -> Wt[64][K] bf16
        int i = (blockIdx.x - nblk) * 256 + threadIdx.x;
        if (i < 128 * 64) {
            int k = i >> 6, n = i & 63;
            W1t[n * 128 + k] = f2bf(W1[i]);
        }
        int j = i - 128 * 64;
        if (j >= 0 && j < 64 * 64) {
            int k = j >> 6, n = j & 63;
            W2t[n * 64 + k] = f2bf(W2[j]);
        }
        return;
    }
    __shared__ int hist[NBMAX];
    int t = threadIdx.x;
    for (int b = t; b < nb; b += 256) hist[b] = 0;
    __syncthreads();
    int base = blockIdx.x * CH;
#pragma unroll
    for (int j = 0; j < CH / 1024; ++j) {
        int idx = base + j * 1024 + t * 4;
        if (idx + 4 <= E) {
            int4 d = *(const int4*)(dst + idx);
            atomicAdd(&hist[d.x >> BSHIFT], 1);
            atomicAdd(&hist[d.y >> BSHIFT], 1);
            atomicAdd(&hist[d.z >> BSHIFT], 1);
            atomicAdd(&hist[d.w >> BSHIFT], 1);
        } else {
            for (int k = 0; k < 4; ++k)
                if (idx + k < E) atomicAdd(&hist[dst[idx + k] >> BSHIFT], 1);
        }
    }
    __syncthreads();
    for (int b = t; b < nb; b += 256) histmat[blockIdx.x * nb + b] = hist[b];
}

// ---------------- pass B: per-bucket scan over blocks (nblk <= 1024) --------
__global__ __launch_bounds__(256) void scancol_kernel(const int* __restrict__ histmat,
                                                      int* __restrict__ colbase,
                                                      int* __restrict__ buckettotal,
                                                      int nb, int nblk) {
    __shared__ int ts[256];
    int b = blockIdx.x;
    int t = threadIdx.x;
    int v[4];
    int tsum = 0;
#pragma unroll
    for (int k = 0; k < 4; ++k) {
        int blk = t * 4 + k;
        v[k] = (blk < nblk) ? histmat[blk * nb + b] : 0;
        tsum += v[k];
    }
    ts[t] = tsum;
    __syncthreads();
    for (int ofs = 1; ofs < 256; ofs <<= 1) {
        int val = (t >= ofs) ? ts[t - ofs] : 0;
        __syncthreads();
        ts[t] += val;
        __syncthreads();
    }
    int run = ts[t] - tsum;
#pragma unroll
    for (int k = 0; k < 4; ++k) {
        int blk = t * 4 + k;
        if (blk < nblk) colbase[blk * nb + b] = run;
        run += v[k];
    }
    if (t == 255) buckettotal[b] = ts[255];
}

// ---------------- pass C: scatter into bucket regions (LDS cursors) ---------
// bucketbase is computed in-block from buckettotal (scanbucket removed).
__global__ __launch_bounds__(256) void bscatter_kernel(const int* __restrict__ src,
                                                       const int* __restrict__ dst,
                                                       const int* __restrict__ colbase,
                                                       const int* __restrict__ buckettotal,
                                                       int* __restrict__ packed,
                                                       int E, int nb) {
    __shared__ int cur[NBMAX];
    __shared__ int ts2[256];
    int t = threadIdx.x;
    // scan buckettotal (782 ints, L2-hot) -> fused with colbase into cursors
    int v4[4];
    int tsum = 0;
#pragma unroll
    for (int k = 0; k < 4; ++k) {
        int bb = t * 4 + k;
        v4[k] = (bb < nb) ? buckettotal[bb] : 0;
        tsum += v4[k];
    }
    ts2[t] = tsum;
    __syncthreads();
    for (int ofs = 1; ofs < 256; ofs <<= 1) {
        int val = (t >= ofs) ? ts2[t - ofs] : 0;
        __syncthreads();
        ts2[t] += val;
        __syncthreads();
    }
    int run = ts2[t] - tsum;
#pragma unroll
    for (int k = 0; k < 4; ++k) {
        int bb = t * 4 + k;
        if (bb < nb) cur[bb] = run + colbase[blockIdx.x * nb + bb];
        run += v4[k];
    }
    __syncthreads();
    int base = blockIdx.x * CH;
#pragma unroll
    for (int j = 0; j < CH / 1024; ++j) {
        int idx = base + j * 1024 + t * 4;
        if (idx + 4 <= E) {
            int4 d = *(const int4*)(dst + idx);
            int4 s = *(const int4*)(src + idx);
            int p;
            p = atomicAdd(&cur[d.x >> BSHIFT], 1); packed[p] = ((d.x & 127) << 17) | s.x;
            p = atomicAdd(&cur[d.y >> BSHIFT], 1); packed[p] = ((d.y & 127) << 17) | s.y;
            p = atomicAdd(&cur[d.z >> BSHIFT], 1); packed[p] = ((d.z & 127) << 17) | s.z;
            p = atomicAdd(&cur[d.w >> BSHIFT], 1); packed[p] = ((d.w & 127) << 17) | s.w;
        } else {
            for (int k = 0; k < 4; ++k)
                if (idx + k < E) {
                    int dd = dst[idx + k], ss = src[idx + k];
                    int p = atomicAdd(&cur[dd >> BSHIFT], 1);
                    packed[p] = ((dd & 127) << 17) | ss;
                }
        }
    }
}

// ---------------- pass D: within-bucket CSR + rowptr + dinv (LDS-cached) ----
__global__ __launch_bounds__(256) void bcsr_kernel(const int* __restrict__ packed,
                                                   const int* __restrict__ buckettotal,
                                                   int* __restrict__ rowptr,
                                                   float* __restrict__ dinv,
                                                   int* __restrict__ csr,
                                                   int N, int nb) {
    __shared__ int deg[128];
    __shared__ int lrp[128];
    __shared__ int ts[128];
    __shared__ int ts2[256];
    __shared__ int shbb[2];
    __shared__ int ebuf[MAXB];
    __shared__ int obuf[MAXB];
    int b = blockIdx.x;
    int t = threadIdx.x;
    if (t < 128) deg[t] = 0;
    // in-block scan of buckettotal to recover [bb0, bb1) for bucket b
    int v4[4];
    int tsum = 0;
#pragma unroll
    for (int k = 0; k < 4; ++k) {
        int bb = t * 4 + k;
        v4[k] = (bb < nb) ? buckettotal[bb] : 0;
        tsum += v4[k];
    }
    ts2[t] = tsum;
    __syncthreads();
    for (int ofs = 1; ofs < 256; ofs <<= 1) {
        int val = (t >= ofs) ? ts2[t - ofs] : 0;
        __syncthreads();
        ts2[t] += val;
        __syncthreads();
    }
    int run = ts2[t] - tsum;
#pragma unroll
    for (int k = 0; k < 4; ++k) {
        int bb = t * 4 + k;
        if (bb == b) { shbb[0] = run; shbb[1] = run + v4[k]; }
        run += v4[k];
    }
    __syncthreads();
    int bb0 = shbb[0];
    int bb1 = shbb[1];
    int cnt = bb1 - bb0;
    bool fits = (cnt <= MAXB);
    if (fits) {
        for (int i = t; i < cnt; i += 256) {
            int v = packed[bb0 + i];
            ebuf[i] = v;
            atomicAdd(&deg[v >> 17], 1);
        }
    } else {
        for (int i = t; i < cnt; i += 256)
            atomicAdd(&deg[packed[bb0 + i] >> 17], 1);
    }
    __syncthreads();
    if (t < 128) ts[t] = deg[t];
    __syncthreads();
    for (int ofs = 1; ofs < 128; ofs <<= 1) {
        int v = (t < 128 && t >= ofs) ? ts[t - ofs] : 0;
        __syncthreads();
        if (t < 128) ts[t] += v;
        __syncthreads();
    }
    int node0 = b << BSHIFT;
    int nlocal = min(128, N - node0);
    if (t < 128) lrp[t] = ts[t] - deg[t];
    if (t < nlocal) {
        rowptr[node0 + t] = bb0 + (ts[t] - deg[t]);
        dinv[node0 + t] = rsqrtf((float)(deg[t] + 1));
    }
    if (t == nlocal) rowptr[node0 + nlocal] = bb1;
    __syncthreads();
    if (fits) {
        for (int i = t; i < cnt; i += 256) {
            int v = ebuf[i];
            int p = atomicAdd(&lrp[v >> 17], 1);
            obuf[p] = v & 0x1FFFF;
        }
        __syncthreads();
        for (int i = t; i < cnt; i += 256) csr[bb0 + i] = obuf[i];  // coalesced
    } else {
        for (int i = t; i < cnt; i += 256) {
            int v = packed[bb0 + i];
            int p = atomicAdd(&lrp[v >> 17], 1);
            csr[bb0 + p] = v & 0x1FFFF;
        }
    }
}

// ------- MFMA GEMM: Ybf[M,64](bf16) = (X[M,K] @ W[K,64]) * dinv[row] -------
template <int K, bool XBF16>
__global__ __launch_bounds__(256) void gemm_mfma(const void* __restrict__ Xv,
                                                 const unsigned short* __restrict__ Wt,
                                                 const float* __restrict__ dinv,
                                                 unsigned short* __restrict__ Ybf, int M) {
    constexpr int KP = K + 8;
    __shared__ unsigned short Xs[64 * KP];   // reused as Cs (64*72) in epilogue
    __shared__ unsigned short Ws[64 * KP];
    int t = threadIdx.x;
    int row0 = blockIdx.x * 64;

    for (int i = t; i < 64 * K / 8; i += 256) {
        int r = i / (K / 8), c8 = i % (K / 8);
        *(uint4*)(&Ws[r * KP + c8 * 8]) = ((const uint4*)Wt)[i];
    }
    if (XBF16) {
        const unsigned short* X = (const unsigned short*)Xv;
        for (int i = t; i < 64 * K / 8; i += 256) {
            int r = i / (K / 8), c8 = i % (K / 8);
            int gr = row0 + r;
            uint4 v = make_uint4(0u, 0u, 0u, 0u);
            if (gr < M) v = ((const uint4*)(X + (size_t)gr * K))[c8];
            *(uint4*)(&Xs[r * KP + c8 * 8]) = v;
        }
    } else {
        const float* X = (const float*)Xv;
        for (int i = t; i < 64 * K / 4; i += 256) {
            int r = i / (K / 4), c4 = i % (K / 4);
            int gr = row0 + r;
            float4 v = make_float4(0.f, 0.f, 0.f, 0.f);
            if (gr < M) v = ((const float4*)(X + (size_t)gr * K))[c4];
            uint2 p;
            p.x = pack2(v.x, v.y);
            p.y = pack2(v.z, v.w);
            *(uint2*)(&Xs[r * KP + c4 * 4]) = p;
        }
    }
    __syncthreads();

    int lane = t & 63;
    int w = t >> 6;
    int m = lane & 15;
    int q = lane >> 4;

    f32x4 acc[4];
#pragma unroll
    for (int nt = 0; nt < 4; ++nt) acc[nt] = (f32x4){0.f, 0.f, 0.f, 0.f};

#pragma unroll
    for (int s = 0; s < K / 32; ++s) {
        bf16x8 a = *(const bf16x8*)(&Xs[(16 * w + m) * KP + s * 32 + q * 8]);
#pragma unroll
        for (int nt = 0; nt < 4; ++nt) {
            bf16x8 b = *(const bf16x8*)(&Ws[(16 * nt + m) * KP + s * 32 + q * 8]);
            acc[nt] = __builtin_amdgcn_mfma_f32_16x16x32_bf16(a, b, acc[nt], 0, 0, 0);
        }
    }
    __syncthreads();

    unsigned short* Cs = Xs;
#pragma unroll
    for (int nt = 0; nt < 4; ++nt)
#pragma unroll
        for (int r = 0; r < 4; ++r) {
            int row = 16 * w + q * 4 + r;
            int gr = row0 + row;
            float d = (gr < M) ? dinv[gr] : 0.f;
            Cs[row * 72 + nt * 16 + m] = f2bf(acc[nt][r] * d);
        }
    __syncthreads();
    for (int i = t; i < 64 * 64 / 8; i += 256) {
        int r = i >> 3, c8 = i & 7;
        int gr = row0 + r;
        if (gr < M)
            *(uint4*)(Ybf + (size_t)gr * 64 + c8 * 8) = *(const uint4*)(&Cs[r * 72 + c8 * 8]);
    }
}

// ---------------- pull aggregation + epilogue ----------------
// DO_GEMM=true (layer 1): o = relu(agg*dinv + b1); then per-block MFMA
//   (H[32][64]bf16 @ W2[64][64]) * dinv -> bf16 table (bufB). gemm2 fused.
// DO_GEMM=false (layer 2): o = agg*dinv + b2 -> fp32 output.
#define ACC8(v)                                      \
    acc[0] += blo(v.x); acc[1] += bhi(v.x);          \
    acc[2] += blo(v.y); acc[3] += bhi(v.y);          \
    acc[4] += blo(v.z); acc[5] += bhi(v.z);          \
    acc[6] += blo(v.w); acc[7] += bhi(v.w);

template <bool DO_GEMM>
__global__ __launch_bounds__(256) void aggregate_kernel(const unsigned* __restrict__ hsu,
                                                        const int* __restrict__ rowptr,
                                                        const int* __restrict__ csr,
                                                        const float* __restrict__ dinv,
                                                        const float* __restrict__ bias,
                                                        const unsigned short* __restrict__ W2t,
                                                        void* __restrict__ outv, int N) {
    __shared__ unsigned short Hs[DO_GEMM ? 32 * 72 : 1];
    __shared__ unsigned short W2s[DO_GEMM ? 64 * 72 : 1];
    __shared__ unsigned short Cs[DO_GEMM ? 32 * 72 : 1];
    int t = threadIdx.x;
    int node0 = blockIdx.x * 32;
    int node = node0 + (t >> 3);
    int sub = t & 7;
    int gbase = t & 56;

    if (DO_GEMM) {
        // stage W2t [64n][64k] bf16 -> LDS (8KB, L2-resident broadcast)
        for (int i = t; i < 64 * 64 / 8; i += 256) {
            int r = i >> 3, c8 = i & 7;
            *(uint4*)(&W2s[r * 72 + c8 * 8]) = ((const uint4*)W2t)[i];
        }
    }

    float acc[8] = {0.f, 0.f, 0.f, 0.f, 0.f, 0.f, 0.f, 0.f};
    if (node < N) {
        {
            uint4 v = *(const uint4*)(hsu + (size_t)node * 32 + sub * 4);  // self-loop
            acc[0] = blo(v.x); acc[1] = bhi(v.x);
            acc[2] = blo(v.y); acc[3] = bhi(v.y);
            acc[4] = blo(v.z); acc[5] = bhi(v.z);
            acc[6] = blo(v.w); acc[7] = bhi(v.w);
        }
        int e0 = rowptr[node];
        int e1 = rowptr[node + 1];
        int e = e0;
        for (; e + 8 <= e1; e += 8) {
            int idx = csr[e + sub];
            int s0 = __shfl(idx, gbase + 0, 64);
            int s1 = __shfl(idx, gbase + 1, 64);
            int s2 = __shfl(idx, gbase + 2, 64);
            int s3 = __shfl(idx, gbase + 3, 64);
            int s4 = __shfl(idx, gbase + 4, 64);
            int s5 = __shfl(idx, gbase + 5, 64);
            int s6 = __shfl(idx, gbase + 6, 64);
            int s7 = __shfl(idx, gbase + 7, 64);
            uint4 v0 = *(const uint4*)(hsu + (size_t)s0 * 32 + sub * 4);
            uint4 v1 = *(const uint4*)(hsu + (size_t)s1 * 32 + sub * 4);
            uint4 v2 = *(const uint4*)(hsu + (size_t)s2 * 32 + sub * 4);
            uint4 v3 = *(const uint4*)(hsu + (size_t)s3 * 32 + sub * 4);
            uint4 v4 = *(const uint4*)(hsu + (size_t)s4 * 32 + sub * 4);
            uint4 v5 = *(const uint4*)(hsu + (size_t)s5 * 32 + sub * 4);
            uint4 v6 = *(const uint4*)(hsu + (size_t)s6 * 32 + sub * 4);
            uint4 v7 = *(const uint4*)(hsu + (size_t)s7 * 32 + sub * 4);
            ACC8(v0); ACC8(v1); ACC8(v2); ACC8(v3);
            ACC8(v4); ACC8(v5); ACC8(v6); ACC8(v7);
        }
        for (; e < e1; ++e) {
            int s = csr[e];
            uint4 v = *(const uint4*)(hsu + (size_t)s * 32 + sub * 4);
            ACC8(v);
        }
    }

    if (DO_GEMM) {
        if (node < N) {
            float d = dinv[node];
            float4 b0 = *(const float4*)(bias + sub * 8);
            float4 b1 = *(const float4*)(bias + sub * 8 + 4);
            float o[8];
            o[0] = fmaxf(fmaf(acc[0], d, b0.x), 0.f);
            o[1] = fmaxf(fmaf(acc[1], d, b0.y), 0.f);
            o[2] = fmaxf(fmaf(acc[2], d, b0.z), 0.f);
            o[3] = fmaxf(fmaf(acc[3], d, b0.w), 0.f);
            o[4] = fmaxf(fmaf(acc[4], d, b1.x), 0.f);
            o[5] = fmaxf(fmaf(acc[5], d, b1.y), 0.f);
            o[6] = fmaxf(fmaf(acc[6], d, b1.z), 0.f);
            o[7] = fmaxf(fmaf(acc[7], d, b1.w), 0.f);
            uint4 p;
            p.x = pack2(o[0], o[1]); p.y = pack2(o[2], o[3]);
            p.z = pack2(o[4], o[5]); p.w = pack2(o[6], o[7]);
            *(uint4*)(&Hs[(t >> 3) * 72 + sub * 8]) = p;  // bf16 h (== old bufB rounding)
        }
        __syncthreads();
        // H[32][64] @ W2[64][64]: 8 16x16 tiles, 2 per wave, K=64 (2 mfma each)
        int lane = t & 63;
        int w = t >> 6;
        int m = lane & 15;
        int q = lane >> 4;
        int mt = w & 1;
#pragma unroll
        for (int half = 0; half < 2; ++half) {
            int nt = (w >> 1) + half * 2;
            f32x4 a4 = (f32x4){0.f, 0.f, 0.f, 0.f};
#pragma unroll
            for (int s = 0; s < 2; ++s) {
                bf16x8 a = *(const bf16x8*)(&Hs[(mt * 16 + m) * 72 + s * 32 + q * 8]);
                bf16x8 b = *(const bf16x8*)(&W2s[(nt * 16 + m) * 72 + s * 32 + q * 8]);
                a4 = __builtin_amdgcn_mfma_f32_16x16x32_bf16(a, b, a4, 0, 0, 0);
            }
#pragma unroll
            for (int r = 0; r < 4; ++r) {
                int row = mt * 16 + q * 4 + r;
                int gn = node0 + row;
                float dd = (gn < N) ? dinv[gn] : 0.f;
                Cs[row * 72 + nt * 16 + m] = f2bf(a4[r] * dd);
            }
        }
        __syncthreads();
        unsigned short* outb = (unsigned short*)outv;
        for (int i = t; i < 32 * 64 / 8; i += 256) {
            int r = i >> 3, c8 = i & 7;
            int gn = node0 + r;
            if (gn < N)
                *(uint4*)(outb + (size_t)gn * 64 + c8 * 8) = *(const uint4*)(&Cs[r * 72 + c8 * 8]);
        }
    } else {
        if (node >= N) return;
        float d = dinv[node];
        float4 b0 = *(const float4*)(bias + sub * 8);
        float4 b1 = *(const float4*)(bias + sub * 8 + 4);
        float o[8];
        o[0] = fmaf(acc[0], d, b0.x); o[1] = fmaf(acc[1], d, b0.y);
        o[2] = fmaf(acc[2], d, b0.z); o[3] = fmaf(acc[3], d, b0.w);
        o[4] = fmaf(acc[4], d, b1.x); o[5] = fmaf(acc[5], d, b1.y);
        o[6] = fmaf(acc[6], d, b1.z); o[7] = fmaf(acc[7], d, b1.w);
        float* op = (float*)outv + (size_t)node * 64 + sub * 8;
        *(float4*)(op)     = make_float4(o[0], o[1], o[2], o[3]);
        *(float4*)(op + 4) = make_float4(o[4], o[5], o[6], o[7]);
    }
}

// ---------------- launch ----------------
extern "C" void kernel_launch(void* const* d_in, const int* in_sizes, int n_in,
                              void* d_out, int out_size, void* d_ws, size_t ws_size,
                              hipStream_t stream) {
    const float* x  = (const float*)d_in[0];
    const int*   ei = (const int*)d_in[1];   // [2, E] int32
    const float* W1 = (const float*)d_in[2];
    const float* b1 = (const float*)d_in[3];
    const float* W2 = (const float*)d_in[4];
    const float* b2 = (const float*)d_in[5];

    const int N = in_sizes[0] / 128;  // 100000
    const int E = in_sizes[1] / 2;    // 3200000
    const int* src = ei;
    const int* dst = ei + E;
    float* out = (float*)d_out;

    const int nb   = (N + 127) >> BSHIFT;  // 782
    const int nblk = (E + CH - 1) / CH;    // 391

    char* ws = (char*)d_ws;
    size_t off = 0;
    auto alloc = [&](size_t bytes) -> char* {
        char* p = ws + off;
        off = (off + bytes + 255) & ~(size_t)255;
        return p;
    };
    // persistent
    int*   csr         = (int*)alloc((size_t)E * 4);
    int*   rowptr      = (int*)alloc((size_t)(N + 1) * 4);
    float* dinv        = (float*)alloc((size_t)N * 4);
    int*   buckettotal = (int*)alloc((size_t)nb * 4);
    unsigned short* W1t = (unsigned short*)alloc(64 * 128 * 2);
    unsigned short* W2t = (unsigned short*)alloc(64 * 64 * 2);
    unsigned short* bufA = (unsigned short*)alloc((size_t)N * 64 * 2);  // bf16 (xW1)*dinv
    unsigned short* bufB = (unsigned short*)alloc((size_t)N * 64 * 2);  // bf16 (hW2)*dinv
    // transient (dead before gemm1 writes bufA) — alias bufA+bufB region
    // histmat: nblk*nb*4 = 391*782*4 ~ 1.22 MB; packed: E*4 = 12.8 MB
    int* histmat = (int*)bufA;
    int* packed  = (int*)((char*)bufA + ((size_t)nblk * nb * 4 + 255 & ~(size_t)255) + 256);

    hist_kernel<<<nblk + 48, 256, 0, stream>>>(dst, histmat, E, nb, nblk, W1, W2, W1t, W2t);
    scancol_kernel<<<nb, 256, 0, stream>>>(histmat, histmat, buckettotal, nb, nblk);
    bscatter_kernel<<<nblk, 256, 0, stream>>>(src, dst, histmat, buckettotal, packed, E, nb);
    bcsr_kernel<<<nb, 256, 0, stream>>>(packed, buckettotal, rowptr, dinv, csr, N, nb);

    gemm_mfma<128, false><<<(N + 63) / 64, 256, 0, stream>>>(x, W1t, dinv, bufA, N);
    aggregate_kernel<true><<<(N + 31) / 32, 256, 0, stream>>>((const unsigned*)bufA, rowptr,
                                                              csr, dinv, b1, W2t, bufB, N);
    aggregate_kernel<false><<<(N + 31) / 32, 256, 0, stream>>>((const unsigned*)bufB, rowptr,
                                                               csr, dinv, b2, W2t, out, N);
}